// Round 1
// baseline (5435.707 us; speedup 1.0000x reference)
//
#include <hip/hip_runtime.h>
#include <math.h>

// GPT-2 small forward: L=4, H=12, E=768, T=1024, B=4, V=50257, D=64
// All activations kept f32; GEMMs cast f32->bf16 during LDS staging and use
// mfma_f32_16x16x32_bf16 with fp32 accumulation.

#define TT 1024
#define BB 4
#define EE 768
#define HH 12
#define DD 64
#define VV 50257
#define NROW 4096           // B*T
#define BTV 205852672L      // B*T*V

typedef __attribute__((ext_vector_type(8))) short short8;
typedef __attribute__((ext_vector_type(4))) float floatx4;

__device__ inline short f2bf(float f) {
    union { float fv; unsigned u; } v; v.fv = f;
    unsigned r = v.u + 0x7FFFu + ((v.u >> 16) & 1u);   // RTNE
    return (short)(r >> 16);
}

// ---------------------------------------------------------------------------
// Generic NT GEMM: C[m,n] = act(alpha * sum_k A[m,k]*B[n,k] + bias[n]) + res
// Batched via z: offset = (z/zdiv)*o?1 + (z%zdiv)*o?2.
// M must be a multiple of 128, K a multiple of 32. N is guarded.
// ---------------------------------------------------------------------------
__global__ __launch_bounds__(256, 2)
void gemm_nt(const float* __restrict__ A, const float* __restrict__ Bw,
             const float* __restrict__ bias, const float* res, float* C,
             int M, int N, int K, int lda, int ldb, int ldc,
             long oA1, long oA2, long oB1, long oB2, long oC1, long oC2,
             int zdiv, float alpha, int act)
{
    const int z = blockIdx.z;
    const long zo = z / zdiv, zi = z % zdiv;
    A  += zo * oA1 + zi * oA2;
    Bw += zo * oB1 + zi * oB2;
    C  += zo * oC1 + zi * oC2;
    const float* R = res ? res + zo * oC1 + zi * oC2 : nullptr;

    __shared__ short As[128][40];   // +8 pad: keeps 16B align, 2-way banks (free)
    __shared__ short Bs[128][40];

    const int tid  = threadIdx.x;
    const int lane = tid & 63;
    const int wave = tid >> 6;
    const int quad = lane >> 4;
    const int l16  = lane & 15;
    const int wm = (wave >> 1) << 6;    // wave row offset (0/64)
    const int wn = (wave & 1) << 6;     // wave col offset (0/64)
    const long m0 = (long)blockIdx.y * 128;
    const long n0 = (long)blockIdx.x * 128;

    floatx4 acc[4][4];
#pragma unroll
    for (int i = 0; i < 4; ++i)
#pragma unroll
        for (int j = 0; j < 4; ++j) acc[i][j] = (floatx4){0.f, 0.f, 0.f, 0.f};

    const int srow = tid >> 3;          // 0..31
    const int sc4  = (tid & 7) * 4;     // 0,4,...,28

    for (int k0 = 0; k0 < K; k0 += 32) {
#pragma unroll
        for (int it = 0; it < 4; ++it) {
            const int row = srow + it * 32;
            // A tile (rows always valid)
            const float4 f = *reinterpret_cast<const float4*>(
                A + (m0 + row) * lda + k0 + sc4);
            As[row][sc4 + 0] = f2bf(f.x);
            As[row][sc4 + 1] = f2bf(f.y);
            As[row][sc4 + 2] = f2bf(f.z);
            As[row][sc4 + 3] = f2bf(f.w);
            // B tile (guard n)
            const long n = n0 + row;
            float4 g = make_float4(0.f, 0.f, 0.f, 0.f);
            if (n < N)
                g = *reinterpret_cast<const float4*>(Bw + n * ldb + k0 + sc4);
            Bs[row][sc4 + 0] = f2bf(g.x);
            Bs[row][sc4 + 1] = f2bf(g.y);
            Bs[row][sc4 + 2] = f2bf(g.z);
            Bs[row][sc4 + 3] = f2bf(g.w);
        }
        __syncthreads();

        short8 af[4], bf[4];
#pragma unroll
        for (int i = 0; i < 4; ++i)
            af[i] = *reinterpret_cast<const short8*>(&As[wm + i * 16 + l16][quad * 8]);
#pragma unroll
        for (int j = 0; j < 4; ++j)
            bf[j] = *reinterpret_cast<const short8*>(&Bs[wn + j * 16 + l16][quad * 8]);
#pragma unroll
        for (int i = 0; i < 4; ++i)
#pragma unroll
            for (int j = 0; j < 4; ++j)
                acc[i][j] = __builtin_amdgcn_mfma_f32_16x16x32_bf16(
                    af[i], bf[j], acc[i][j], 0, 0, 0);
        __syncthreads();
    }

    // Epilogue: C/D layout row = quad*4 + r, col = l16
#pragma unroll
    for (int i = 0; i < 4; ++i) {
        const long mbase = m0 + wm + i * 16 + quad * 4;
#pragma unroll
        for (int j = 0; j < 4; ++j) {
            const long n = n0 + wn + j * 16 + l16;
            if (n < N) {
                const float bv = bias ? bias[n] : 0.f;
#pragma unroll
                for (int r = 0; r < 4; ++r) {
                    float v = acc[i][j][r] * alpha + bv;
                    if (act == 1) {
                        const float u = v;
                        v = 0.5f * u * (1.f + tanhf(0.7978845608f * (u + 0.044715f * u * u * u)));
                    }
                    const long ci = (mbase + r) * ldc + n;
                    if (R) v += R[ci];
                    C[ci] = v;
                }
            }
        }
    }
}

// ---------------------------------------------------------------------------
// x[row,:] = wte[idx[row],:] + wpe[row%T,:]
// ---------------------------------------------------------------------------
__global__ __launch_bounds__(256)
void embed_kernel(const int* __restrict__ idx, const float* __restrict__ wte,
                  const float* __restrict__ wpe, float* __restrict__ x)
{
    const int row = blockIdx.x;
    const int t = row & (TT - 1);
    const long wrow = (long)idx[row] * EE;
#pragma unroll
    for (int i = 0; i < 3; ++i) {
        const int e = threadIdx.x + i * 256;
        x[(long)row * EE + e] = wte[wrow + e] + wpe[(long)t * EE + e];
    }
}

// ---------------------------------------------------------------------------
// LayerNorm row kernel (E=768, block=256, 3 elems/thread)
// ---------------------------------------------------------------------------
__global__ __launch_bounds__(256)
void ln_kernel(const float* __restrict__ x, const float* __restrict__ w,
               const float* __restrict__ b, float* __restrict__ out)
{
    const int row = blockIdx.x;
    const int tid = threadIdx.x;
    const float* xr = x + (long)row * EE;
    const float v0 = xr[tid], v1 = xr[tid + 256], v2 = xr[tid + 512];

    __shared__ float s1[256], s2[256];
    s1[tid] = v0 + v1 + v2;
    s2[tid] = v0 * v0 + v1 * v1 + v2 * v2;
    __syncthreads();
    for (int st = 128; st > 0; st >>= 1) {
        if (tid < st) { s1[tid] += s1[tid + st]; s2[tid] += s2[tid + st]; }
        __syncthreads();
    }
    const float mean = s1[0] * (1.f / EE);
    const float var  = s2[0] * (1.f / EE) - mean * mean;
    const float rs   = rsqrtf(var + 1e-5f);
    float* orow = out + (long)row * EE;
    orow[tid]       = (v0 - mean) * rs * w[tid]       + b[tid];
    orow[tid + 256] = (v1 - mean) * rs * w[tid + 256] + b[tid + 256];
    orow[tid + 512] = (v2 - mean) * rs * w[tid + 512] + b[tid + 512];
}

// ---------------------------------------------------------------------------
// V transpose: vt[(b*H+h)*D + d][t] = qkv[b, t, 2E + h*D + d]
// ---------------------------------------------------------------------------
__global__ __launch_bounds__(256)
void vtrans_kernel(const float* __restrict__ qkv, float* __restrict__ vt)
{
    const int z = blockIdx.y;           // b*H + h
    const int b = z / HH, h = z % HH;
    const int t0 = blockIdx.x * 64;
    __shared__ float tile[64][65];
    const int tid = threadIdx.x;
#pragma unroll
    for (int i = 0; i < 16; ++i) {
        const int lin = i * 256 + tid;
        const int r = lin >> 6, c = lin & 63;   // r = t-local, c = d
        tile[r][c] = qkv[((long)(b * TT + t0 + r)) * (3 * EE) + 2 * EE + h * DD + c];
    }
    __syncthreads();
#pragma unroll
    for (int i = 0; i < 16; ++i) {
        const int lin = i * 256 + tid;
        const int r = lin >> 6, c = lin & 63;   // r = d, c = t-local
        vt[((long)(z * DD + r)) * TT + t0 + c] = tile[c][r];
    }
}

// ---------------------------------------------------------------------------
// Causal softmax: row (z,q) of att (48,1024,1024) f32 -> p f32 (zeros k>q)
// ---------------------------------------------------------------------------
__global__ __launch_bounds__(256)
void softmax_kernel(const float* __restrict__ att, float* __restrict__ p)
{
    const int q = blockIdx.x, z = blockIdx.y;
    const float* row = att + ((long)z * TT + q) * TT;
    float* prow = p + ((long)z * TT + q) * TT;
    const int tid = threadIdx.x;

    float rv[4];
#pragma unroll
    for (int i = 0; i < 4; ++i) rv[i] = row[tid + i * 256];

    __shared__ float sm[256];
    float m = -INFINITY;
#pragma unroll
    for (int i = 0; i < 4; ++i)
        if (tid + i * 256 <= q) m = fmaxf(m, rv[i]);
    sm[tid] = m; __syncthreads();
    for (int st = 128; st > 0; st >>= 1) {
        if (tid < st) sm[tid] = fmaxf(sm[tid], sm[tid + st]);
        __syncthreads();
    }
    const float mx = sm[0];
    __syncthreads();

    float s = 0.f;
#pragma unroll
    for (int i = 0; i < 4; ++i)
        if (tid + i * 256 <= q) s += __expf(rv[i] - mx);
    sm[tid] = s; __syncthreads();
    for (int st = 128; st > 0; st >>= 1) {
        if (tid < st) sm[tid] += sm[tid + st];
        __syncthreads();
    }
    const float inv = 1.f / sm[0];
#pragma unroll
    for (int i = 0; i < 4; ++i) {
        const int k = tid + i * 256;
        prow[k] = (k <= q) ? __expf(rv[i] - mx) * inv : 0.f;
    }
}

// ---------------------------------------------------------------------------
// Cross-entropy: one block per (b,t), t<T-1. Online logsumexp over V.
// ---------------------------------------------------------------------------
__global__ __launch_bounds__(256)
void loss_kernel(const float* __restrict__ logits, const int* __restrict__ targets,
                 float* __restrict__ loss)
{
    const int rid = blockIdx.x;             // b*T + t
    if ((rid & (TT - 1)) == TT - 1) return; // skip t == T-1
    const float* row = logits + (long)rid * VV;
    const int tid = threadIdx.x;

    float m = -INFINITY, s = 0.f;
    for (int k = tid; k < VV; k += 256) {
        const float v = row[k];
        if (v > m) { s = s * __expf(m - v) + 1.f; m = v; }
        else         s += __expf(v - m);
    }
    __shared__ float sm[256], ss[256];
    sm[tid] = m; ss[tid] = s; __syncthreads();
    for (int st = 128; st > 0; st >>= 1) {
        if (tid < st) {
            float m1 = sm[tid], s1 = ss[tid];
            float m2 = sm[tid + st], s2 = ss[tid + st];
            if (m2 > m1) { float tm = m1; m1 = m2; m2 = tm; float ts = s1; s1 = s2; s2 = ts; }
            if (m2 != -INFINITY) s1 += s2 * __expf(m2 - m1);
            sm[tid] = m1; ss[tid] = s1;
        }
        __syncthreads();
    }
    if (tid == 0) {
        const float lse = sm[0] + __logf(ss[0]);
        atomicAdd(loss, (lse - row[targets[rid + 1]]) * (1.f / 4092.f));
    }
}

// ---------------------------------------------------------------------------
extern "C" void kernel_launch(void* const* d_in, const int* in_sizes, int n_in,
                              void* d_out, int out_size, void* d_ws, size_t ws_size,
                              hipStream_t stream)
{
    const int*   idx     = (const int*)d_in[0];
    const int*   targets = (const int*)d_in[1];
    const float* wte     = (const float*)d_in[2];
    const float* wpe     = (const float*)d_in[3];
    const float* ln1_w   = (const float*)d_in[4];
    const float* ln1_b   = (const float*)d_in[5];
    const float* attn_w  = (const float*)d_in[6];
    const float* attn_b  = (const float*)d_in[7];
    const float* proj_w  = (const float*)d_in[8];
    const float* proj_b  = (const float*)d_in[9];
    const float* ln2_w   = (const float*)d_in[10];
    const float* ln2_b   = (const float*)d_in[11];
    const float* fc_w    = (const float*)d_in[12];
    const float* fc_b    = (const float*)d_in[13];
    const float* out_w   = (const float*)d_in[14];
    const float* out_b   = (const float*)d_in[15];
    const float* lnf_w   = (const float*)d_in[16];
    const float* lnf_b   = (const float*)d_in[17];

    // workspace layout (f32 elements)
    float* xbuf = (float*)d_ws;             // 4096*768
    float* hbuf = xbuf + 3145728;           // 4096*768
    float* qkv  = hbuf + 3145728;           // 4096*2304
    float* vt   = qkv  + 9437184;           // 48*64*1024
    float* ybuf = vt   + 3145728;           // 4096*768
    float* fcb  = ybuf + 3145728;           // 4096*3072

    // d_out doubles as attention scratch until the logits GEMM
    float* att    = (float*)d_out;          // 48*1024*1024
    float* pbuf   = att + 50331648;         // 48*1024*1024
    float* logits = (float*)d_out;
    float* loss   = (float*)d_out + BTV;

    const dim3 blk(256);

    embed_kernel<<<dim3(NROW), blk, 0, stream>>>(idx, wte, wpe, xbuf);

    for (int l = 0; l < 4; ++l) {
        ln_kernel<<<dim3(NROW), blk, 0, stream>>>(xbuf, ln1_w + l * EE, ln1_b + l * EE, hbuf);

        // qkv = h @ attn_w^T + attn_b     (4096 x 2304 x 768)
        gemm_nt<<<dim3(18, 32, 1), blk, 0, stream>>>(
            hbuf, attn_w + (long)l * 2304 * EE, attn_b + l * 2304, nullptr, qkv,
            NROW, 2304, EE, EE, EE, 2304,
            0L, 0L, 0L, 0L, 0L, 0L, 1, 1.0f, 0);

        // scores = q @ k^T * 0.125        (48 batched 1024 x 1024 x 64)
        gemm_nt<<<dim3(8, 8, 48), blk, 0, stream>>>(
            qkv, qkv + EE, nullptr, nullptr, att,
            TT, TT, DD, 3 * EE, 3 * EE, TT,
            2359296L, 64L, 2359296L, 64L, 12582912L, 1048576L, HH, 0.125f, 0);

        softmax_kernel<<<dim3(TT, 48), blk, 0, stream>>>(att, pbuf);
        vtrans_kernel<<<dim3(16, 48), blk, 0, stream>>>(qkv, vt);

        // y = p @ v                        (48 batched 1024 x 64 x 1024)
        gemm_nt<<<dim3(1, 8, 48), blk, 0, stream>>>(
            pbuf, vt, nullptr, nullptr, ybuf,
            TT, DD, TT, TT, TT, EE,
            12582912L, 1048576L, 786432L, 65536L, 786432L, 64L, HH, 1.0f, 0);

        // x = x + y @ proj_w^T + proj_b    (4096 x 768 x 768)
        gemm_nt<<<dim3(6, 32, 1), blk, 0, stream>>>(
            ybuf, proj_w + (long)l * EE * EE, proj_b + l * EE, xbuf, xbuf,
            NROW, EE, EE, EE, EE, EE,
            0L, 0L, 0L, 0L, 0L, 0L, 1, 1.0f, 0);

        ln_kernel<<<dim3(NROW), blk, 0, stream>>>(xbuf, ln2_w + l * EE, ln2_b + l * EE, hbuf);

        // fc = gelu(h @ fc_w^T + fc_b)     (4096 x 3072 x 768)
        gemm_nt<<<dim3(24, 32, 1), blk, 0, stream>>>(
            hbuf, fc_w + (long)l * 3072 * EE, fc_b + l * 3072, nullptr, fcb,
            NROW, 3072, EE, EE, EE, 3072,
            0L, 0L, 0L, 0L, 0L, 0L, 1, 1.0f, 1);

        // x = x + fc @ out_w^T + out_b     (4096 x 768 x 3072)
        gemm_nt<<<dim3(6, 32, 1), blk, 0, stream>>>(
            fcb, out_w + (long)l * EE * 3072, out_b + l * EE, xbuf, xbuf,
            NROW, EE, 3072, 3072, 3072, EE,
            0L, 0L, 0L, 0L, 0L, 0L, 1, 1.0f, 0);
    }

    ln_kernel<<<dim3(NROW), blk, 0, stream>>>(xbuf, lnf_w, lnf_b, hbuf);

    // logits = h @ wte^T                  (4096 x 50257 x 768)
    gemm_nt<<<dim3(393, 32, 1), blk, 0, stream>>>(
        hbuf, wte, nullptr, nullptr, logits,
        NROW, VV, EE, EE, EE, VV,
        0L, 0L, 0L, 0L, 0L, 0L, 1, 1.0f, 0);

    hipMemsetAsync(loss, 0, sizeof(float), stream);
    loss_kernel<<<dim3(NROW), blk, 0, stream>>>(logits, targets, loss);
}